// Round 4
// baseline (5018.013 us; speedup 1.0000x reference)
//
#include <hip/hip_runtime.h>
#include <hip/hip_bf16.h>

// BiLSTM-CRF loss, MI355X. B=64 T=512 V=30000 E=256 H=512 C=9.
// Round 4: cooperative LDS staging of the h exchange (contiguous 256B/lane
// sc-loads -> 128B fabric packets), single-poller-per-WG flags, 16B gathered
// sc-stores. Whh+Wih fragments register-resident; h A-frags from swizzled LDS.

using short8 = __attribute__((ext_vector_type(8))) short;   // 8 x bf16 bits
using f32x4  = __attribute__((ext_vector_type(4))) float;
using i32x4  = __attribute__((ext_vector_type(4))) int;

#define TT 512
#define BB 64

__device__ __forceinline__ unsigned short f2bf(float f) {
  unsigned int u = __builtin_bit_cast(unsigned int, f);
  u += 0x7FFFu + ((u >> 16) & 1u);           // RNE
  return (unsigned short)(u >> 16);
}
__device__ __forceinline__ float bf2f(short s) {
  unsigned int u = ((unsigned int)(unsigned short)s) << 16;
  return __builtin_bit_cast(float, u);
}
__device__ __forceinline__ float fast_rcp(float x) { return __builtin_amdgcn_rcpf(x); }
__device__ __forceinline__ float sigmoid_f(float x) { return fast_rcp(1.f + __expf(-x)); }
__device__ __forceinline__ float tanh_f(float x) {
  float e = __expf(-2.f * fabsf(x));
  float r = (1.f - e) * fast_rcp(1.f + e);
  return copysignf(r, x);
}
#define SEL4(i, a0, a1, a2, a3) ((i)==0?(a0):((i)==1?(a1):((i)==2?(a2):(a3))))

// ---- uncached (coherence-point) ops: sc0 sc1 ----
__device__ __forceinline__ i32x4 load16_sc(const void* p) {      // no wait
  i32x4 r;
  asm volatile("global_load_dwordx4 %0, %1, off sc0 sc1" : "=v"(r) : "v"(p));
  return r;
}
__device__ __forceinline__ i32x4 load16_sc_wait(const void* p) { // self-waiting
  i32x4 r;
  asm volatile("global_load_dwordx4 %0, %1, off sc0 sc1\n\ts_waitcnt vmcnt(0)"
               : "=v"(r) : "v"(p) : "memory");
  return r;
}
__device__ __forceinline__ void store16_sc(void* p, i32x4 v) {
  asm volatile("global_store_dwordx4 %0, %1, off sc0 sc1" :: "v"(p), "v"(v) : "memory");
}
#define WAITV(n) do { asm volatile("s_waitcnt vmcnt(" #n ")" ::: "memory"); \
                      __builtin_amdgcn_sched_barrier(0); } while (0)

// ---------------- K0a: pack LSTM + FC weights to bf16 -----------------------
// LSTM col n in [0,64) of block bid (d=bid&1, sl=bid>>1):
//   gate g=n&3, jq=(n>>2)&3, tj=(n>>4)&1, nt=n>>5 -> unit jj = nt*8+jq*2+tj,
//   weight row r = g*512 + sl*16 + jj.  (unit permutation enables wide stores)
__global__ void pack_weights(const float* __restrict__ Wih_f, const float* __restrict__ Whh_f,
                             const float* __restrict__ Wih_b, const float* __restrict__ Whh_b,
                             const float* __restrict__ Wfc,
                             short* __restrict__ WpackX, short* __restrict__ WpackH,
                             short* __restrict__ WfcPack) {
  const int bid = blockIdx.x;
  const int d = bid & 1, sl = bid >> 1;
  const float* Wih = d ? Wih_b : Wih_f;
  const float* Whh = d ? Whh_b : Whh_f;
  for (int idx = threadIdx.x; idx < 64 * 256; idx += 256) {
    int n = idx >> 8, k = idx & 255;
    int g = n & 3, jq = (n >> 2) & 3, tj = (n >> 4) & 1, nt = n >> 5;
    int r = g * 512 + sl * 16 + nt * 8 + jq * 2 + tj;
    WpackX[((size_t)bid * 64 + n) * 256 + k] = (short)f2bf(Wih[(size_t)r * 256 + k]);
  }
  for (int idx = threadIdx.x; idx < 64 * 512; idx += 256) {
    int n = idx >> 9, k = idx & 511;
    int g = n & 3, jq = (n >> 2) & 3, tj = (n >> 4) & 1, nt = n >> 5;
    int r = g * 512 + sl * 16 + nt * 8 + jq * 2 + tj;
    WpackH[((size_t)bid * 64 + n) * 512 + k] = (short)f2bf(Whh[(size_t)r * 512 + k]);
  }
  if (bid == 0) {
    for (int idx = threadIdx.x; idx < 16 * 1024; idx += 256) {
      int c = idx >> 10, k = idx & 1023;
      WfcPack[idx] = (c < 9) ? (short)f2bf(Wfc[c * 1024 + k]) : (short)0;
    }
  }
}

// ---------------- K0b: gather embeddings into MFMA A-fragment layout --------
__global__ void pack_x(const int* __restrict__ x, const float* __restrict__ emb,
                       short* __restrict__ xpack) {
  int gid = blockIdx.x * 256 + threadIdx.x;     // < 1048576
  int lane = gid & 63;
  int kc = (gid >> 6) & 7;
  int mt = (gid >> 9) & 3;
  int t  = gid >> 11;
  int b  = mt * 16 + (lane & 15);
  int k0 = kc * 32 + (lane >> 4) * 8;
  int vid = x[b * TT + t];
  const float* e = emb + (size_t)vid * 256 + k0;
  short8 v;
#pragma unroll
  for (int i = 0; i < 8; ++i) v[i] = (short)f2bf(e[i]);
  *reinterpret_cast<short8*>(xpack + (size_t)gid * 8) = v;
}

// ---------------- K0c: zero flags -------------------------------------------
__global__ void init_state(int* __restrict__ flags) {
  flags[threadIdx.x] = 0;                       // 256 flags
}

// ---------------- K1: persistent flag-synced BiLSTM -------------------------
// 64 WGs x 256 thr. WG: d=bid&1, sl=bid>>1 owns 16 units x 4 gates.
// Wave (mtb=wv&1, nt=wv>>1): rows [mtb*32,+32) x 8 units.
// Per step: x-MFMA (regs) -> wave0 polls 128 dir flags -> barrier ->
// cooperative sc-load h[64x512] -> swizzled LDS -> barrier -> h-MFMA from
// LDS -> epilogue (shuffle gates, activations, gathered 16B sc-stores,
// vmcnt ack, flag publish).
__launch_bounds__(256, 1)
__global__ void lstm_step_kernel(const short8* __restrict__ xpack,
                                 const short* __restrict__ WpackX,
                                 const short* __restrict__ WpackH,
                                 short* __restrict__ hping,   // [2][2][64][512]
                                 int* __restrict__ flags,     // [2][2][64]
                                 short* __restrict__ hhist,   // [2][512][64][512]
                                 const float* __restrict__ b_f,
                                 const float* __restrict__ b_b,
                                 const int* __restrict__ seq_len) {
  const int bid = blockIdx.x;
  const int d = bid & 1;
  const int sl = bid >> 1;
  const int tid = threadIdx.x;
  const int wv = tid >> 6;
  const int lane = tid & 63;
  const int l15 = lane & 15;
  const int lhi = lane >> 4;
  const int q = lane & 3;          // gate id of this lane's column
  const int jq = l15 >> 2;
  const int mtb = wv & 1;          // wave's row half
  const int nt = wv >> 1;          // wave's 8-unit group
  const int mbase = mtb * 32;
  const int nbase = nt * 32;
  const int ubase = sl * 16 + nt * 8;            // wave's 8-unit base

  __shared__ short hlds[64 * 512];               // 64 KB swizzled h tile

  // Wih + Whh B-fragments, register-resident for the whole kernel.
  short8 bfx[2][8];
#pragma unroll
  for (int tj = 0; tj < 2; ++tj)
#pragma unroll
    for (int kc = 0; kc < 8; ++kc)
      bfx[tj][kc] = *reinterpret_cast<const short8*>(
          WpackX + ((size_t)bid * 64 + nbase + tj * 16 + l15) * 256 + kc * 32 + lhi * 8);
  short8 bfh[2][16];
#pragma unroll
  for (int tj = 0; tj < 2; ++tj)
#pragma unroll
    for (int kc = 0; kc < 16; ++kc)
      bfh[tj][kc] = *reinterpret_cast<const short8*>(
          WpackH + ((size_t)bid * 64 + nbase + tj * 16 + l15) * 512 + kc * 32 + lhi * 8);

  const float* bias = d ? b_b : b_f;
  float bi[2], bfg[2], bgg[2], bog[2];
#pragma unroll
  for (int tj = 0; tj < 2; ++tj) {
    int jg = ubase + jq * 2 + tj;
    bi[tj]  = bias[jg];
    bfg[tj] = bias[512 + jg];
    bgg[tj] = bias[1024 + jg];
    bog[tj] = bias[1536 + jg];
  }
  int brow[2], Lr[2];
#pragma unroll
  for (int ti = 0; ti < 2; ++ti) {
    brow[ti] = mbase + ti * 16 + lhi * 4 + q;   // this lane's batch row
    Lr[ti] = seq_len[brow[ti]];
  }
  float cst[2][2] = {{0.f, 0.f}, {0.f, 0.f}};
  float hst[2][2] = {{0.f, 0.f}, {0.f, 0.f}};

  int* fl_mine = flags + (d * 2 + mtb) * 64 + (sl * 2 + nt);  // this wave's flag
  const int* fl_dir = flags + d * 128;                        // 128 flags of dir

  for (int s = 0; s < TT; ++s) {
    const int t = d ? (TT - 1 - s) : s;
    f32x4 acc[2][2];
#pragma unroll
    for (int ti = 0; ti < 2; ++ti)
#pragma unroll
      for (int tj = 0; tj < 2; ++tj) acc[ti][tj] = (f32x4){0.f, 0.f, 0.f, 0.f};

    // ---- Phase A: x@Wih^T (no sequential dependency) ----
    const short8* xp = xpack + (size_t)t * 2048;
#pragma unroll
    for (int kc = 0; kc < 8; ++kc) {
      short8 af[2];
#pragma unroll
      for (int ti = 0; ti < 2; ++ti)
        af[ti] = xp[((mtb * 2 + ti) * 8 + kc) * 64 + lane];
#pragma unroll
      for (int ti = 0; ti < 2; ++ti)
#pragma unroll
        for (int tj = 0; tj < 2; ++tj)
          acc[ti][tj] = __builtin_amdgcn_mfma_f32_16x16x32_bf16(af[ti], bfx[tj][kc], acc[ti][tj], 0, 0, 0);
    }

    if (s > 0) {
      // ---- Phase B: wave 0 polls all 128 flags of this direction ----
      if (wv == 0) {
        const int* myq = fl_dir + (lane & 31) * 4;
        int vtries = 0;
        while (true) {
          i32x4 f = load16_sc_wait(myq);
          bool ok = (f[0] >= s) & (f[1] >= s) & (f[2] >= s) & (f[3] >= s);
          if (__all(ok)) break;
          __builtin_amdgcn_s_sleep(1);
          if (++vtries > (1 << 17)) break;     // anti-hang valve
        }
      }
      __syncthreads();

      // ---- Phase C: cooperative stage h[64][512] -> swizzled LDS ----
      {
        const short* hp = hping + ((size_t)(d * 2 + (s & 1)) * 64) * 512;
        const int r = wv * 16 + (lane >> 2);
        const int bo = (lane & 3) * 256;       // byte offset within 1KB row
        const char* src = (const char*)(hp + r * 512) + bo;
        char* dst = (char*)hlds + r * 1024;
        const int swz = (r & 7) << 4;
        i32x4 v[8], w[8];
        WAITV(0);                              // isolate vmcnt to our loads
#pragma unroll
        for (int k = 0; k < 8; ++k) v[k] = load16_sc(src + k * 16);
#pragma unroll
        for (int k = 0; k < 8; ++k) w[k] = load16_sc(src + 128 + k * 16);
        WAITV(8);
#pragma unroll
        for (int k = 0; k < 8; ++k)
          *(i32x4*)(dst + ((bo + k * 16) ^ swz)) = v[k];
        WAITV(0);
#pragma unroll
        for (int k = 0; k < 8; ++k)
          *(i32x4*)(dst + ((bo + 128 + k * 16) ^ swz)) = w[k];
      }
      __syncthreads();

      // ---- Phase D: h@Whh^T from swizzled LDS ----
#pragma unroll
      for (int kc = 0; kc < 16; ++kc) {
        short8 af[2];
#pragma unroll
        for (int ti = 0; ti < 2; ++ti) {
          int row = mbase + ti * 16 + l15;
          af[ti] = *(const short8*)((const char*)hlds + row * 1024
                                    + ((kc * 64 + lhi * 16) ^ ((row & 7) << 4)));
        }
#pragma unroll
        for (int ti = 0; ti < 2; ++ti)
#pragma unroll
          for (int tj = 0; tj < 2; ++tj)
            acc[ti][tj] = __builtin_amdgcn_mfma_f32_16x16x32_bf16(af[ti], bfh[tj][kc], acc[ti][tj], 0, 0, 0);
      }
    }

    // ---- Phase E: gates via 4-lane shuffles, state update, wide stores ----
    short* hpo = hping + ((size_t)(d * 2 + ((s + 1) & 1)) * 64) * 512;
#pragma unroll
    for (int ti = 0; ti < 2; ++ti) {
      bool m = (t < Lr[ti]);
      unsigned short hnb[2], htb[2];
#pragma unroll
      for (int tj = 0; tj < 2; ++tj) {
        f32x4 A = acc[ti][tj];
        float a0 = A[0], a1 = A[1], a2 = A[2], a3 = A[3];
        float e10 = __shfl_xor(a0, 1, 64), e11 = __shfl_xor(a1, 1, 64),
              e12 = __shfl_xor(a2, 1, 64), e13 = __shfl_xor(a3, 1, 64);
        float e20 = __shfl_xor(a0, 2, 64), e21 = __shfl_xor(a1, 2, 64),
              e22 = __shfl_xor(a2, 2, 64), e23 = __shfl_xor(a3, 2, 64);
        float e30 = __shfl_xor(a0, 3, 64), e31 = __shfl_xor(a1, 3, 64),
              e32 = __shfl_xor(a2, 3, 64), e33 = __shfl_xor(a3, 3, 64);
        float g0 = SEL4(q, a0, a1, a2, a3);
        float g1 = SEL4(q, e10, e11, e12, e13);
        float g2 = SEL4(q, e20, e21, e22, e23);
        float g3 = SEL4(q, e30, e31, e32, e33);
        float gi = SEL4(q,     g0, g1, g2, g3) + bi[tj];
        float gf = SEL4(q ^ 1, g0, g1, g2, g3) + bfg[tj];
        float gg = SEL4(q ^ 2, g0, g1, g2, g3) + bgg[tj];
        float go = SEL4(q ^ 3, g0, g1, g2, g3) + bog[tj];
        float si = sigmoid_f(gi), sf = sigmoid_f(gf), so = sigmoid_f(go);
        float ct = sf * cst[ti][tj] + si * tanh_f(gg);
        float ht = so * tanh_f(ct);
        float cn = m ? ct : cst[ti][tj];
        float hn = m ? ht : hst[ti][tj];
        cst[ti][tj] = cn;
        hst[ti][tj] = hn;
        hnb[tj] = f2bf(hn);
        htb[tj] = m ? f2bf(ht) : (unsigned short)0;
      }
      unsigned int up = ((unsigned int)hnb[1] << 16) | hnb[0];
      unsigned int uh = ((unsigned int)htb[1] << 16) | htb[0];
      // gather the row's 4 unit-pairs (jq=0..3 at lanes +4,+8,+12) into jq==0
      unsigned int p1 = __shfl_xor(up, 4, 64), p2 = __shfl_xor(up, 8, 64),
                   p3 = __shfl_xor(up, 12, 64);
      unsigned int q1 = __shfl_xor(uh, 4, 64), q2 = __shfl_xor(uh, 8, 64),
                   q3 = __shfl_xor(uh, 12, 64);
      if (jq == 0) {
        i32x4 packp = {(int)up, (int)p1, (int)p2, (int)p3};
        store16_sc(hpo + brow[ti] * 512 + ubase, packp);
        i32x4 packh = {(int)uh, (int)q1, (int)q2, (int)q3};
        *reinterpret_cast<i32x4*>(
            &hhist[(((size_t)d * TT + t) * 64 + brow[ti]) * 512 + ubase]) = packh;
      }
    }
    // publish this wave's flag after its h-stores are globally visible
    if (lane == 0) {
      int sv = s + 1;
      asm volatile("s_waitcnt vmcnt(0)\n\t"
                   "global_store_dword %0, %1, off sc0 sc1"
                   :: "v"(fl_mine), "v"(sv) : "memory");
    }
  }
}

// ---------------- K2: emission logits = [hf|hb] @ Wfc^T via MFMA ------------
__launch_bounds__(256)
__global__ void emis_kernel(const short* __restrict__ hhist,
                            const short* __restrict__ WfcPack,
                            float* __restrict__ logits) {
  __shared__ short wfc[16 * 1032];             // padded stride vs bank conflicts
  const int tid = threadIdx.x;
  for (int idx = tid; idx < 2048; idx += 256) {
    int n = idx >> 7, c8 = idx & 127;
    short8 v = *reinterpret_cast<const short8*>(WfcPack + n * 1024 + c8 * 8);
    *reinterpret_cast<short8*>(&wfc[n * 1032 + c8 * 8]) = v;
  }
  __syncthreads();
  const int wv = tid >> 6, lane = tid & 63;
  const int l15 = lane & 15, lhi = lane >> 4;
#pragma unroll
  for (int mt2 = 0; mt2 < 2; ++mt2) {
    int m = (blockIdx.x * 4 + wv) * 2 + mt2;
    int r0 = m * 16;
    f32x4 acc = (f32x4){0.f, 0.f, 0.f, 0.f};
#pragma unroll
    for (int kc = 0; kc < 32; ++kc) {
      const short* pa = hhist + ((kc < 16) ? 0 : (size_t)16777216)
                        + (size_t)(r0 + l15) * 512 + (kc & 15) * 32 + lhi * 8;
      short8 a = *reinterpret_cast<const short8*>(pa);
      short8 b = *reinterpret_cast<const short8*>(&wfc[l15 * 1032 + kc * 32 + lhi * 8]);
      acc = __builtin_amdgcn_mfma_f32_16x16x32_bf16(a, b, acc, 0, 0, 0);
    }
    int c = l15;
    if (c < 9) {
#pragma unroll
      for (int reg = 0; reg < 4; ++reg) {
        int rr = r0 + lhi * 4 + reg;
        int b = rr & 63, t = rr >> 6;
        logits[((size_t)b * TT + t) * 9 + c] = acc[reg];
      }
    }
  }
}

// ---------------- K3: CRF numerator + forward algorithm per batch -----------
__global__ void crf_kernel(const float* __restrict__ logits, const int* __restrict__ y,
                           const int* __restrict__ seq_len, const float* __restrict__ start_t,
                           const float* __restrict__ end_t, const float* __restrict__ trans,
                           float* __restrict__ partials) {
  const int b = blockIdx.x;
  const int lane = threadIdx.x;          // 64
  const float* lg = logits + (size_t)b * TT * 9;
  const int* yb = y + b * TT;
  const int L = seq_len[b];

  float acc = 0.f;
  for (int t = lane; t < TT; t += 64) {
    if (t < L) {
      float mx = lg[t * 9];
      for (int c = 1; c < 9; ++c) mx = fmaxf(mx, lg[t * 9 + c]);
      float se = 0.f;
      for (int c = 0; c < 9; ++c) se += __expf(lg[t * 9 + c] - mx);
      float lse = mx + __logf(se);
      int yt = yb[t];
      acc += lg[t * 9 + yt] - lse;
      if (t >= 1) acc += trans[yb[t - 1] * 9 + yt];
    }
  }
#pragma unroll
  for (int off = 32; off >= 1; off >>= 1) acc += __shfl_down(acc, off, 64);

  const int c = (lane < 9) ? lane : 0;
  float score;
  {
    float mx = lg[0];
    for (int cc = 1; cc < 9; ++cc) mx = fmaxf(mx, lg[cc]);
    float se = 0.f;
    for (int cc = 0; cc < 9; ++cc) se += __expf(lg[cc] - mx);
    score = start_t[c] + lg[c] - (mx + __logf(se));
  }
  float tr[9];
#pragma unroll
  for (int cc = 0; cc < 9; ++cc) tr[cc] = trans[cc * 9 + c];
  for (int t = 1; t < L; ++t) {
    const float* lt = lg + t * 9;
    float mx2 = lt[0];
    for (int cc = 1; cc < 9; ++cc) mx2 = fmaxf(mx2, lt[cc]);
    float se2 = 0.f;
    for (int cc = 0; cc < 9; ++cc) se2 += __expf(lt[cc] - mx2);
    float em = lt[c] - (mx2 + __logf(se2));
    float vv[9];
    float mx = -1e30f;
#pragma unroll
    for (int cc = 0; cc < 9; ++cc) {
      float sp = __shfl(score, cc, 64);
      vv[cc] = sp + tr[cc];
      mx = fmaxf(mx, vv[cc]);
    }
    float se = 0.f;
#pragma unroll
    for (int cc = 0; cc < 9; ++cc) se += __expf(vv[cc] - mx);
    score = mx + __logf(se) + em;
  }
  float val = (lane < 9) ? (score + end_t[lane]) : -1e30f;
  float mm = val;
#pragma unroll
  for (int off = 1; off < 64; off <<= 1) mm = fmaxf(mm, __shfl_xor(mm, off, 64));
  float se = (lane < 9) ? __expf(val - mm) : 0.f;
#pragma unroll
  for (int off = 1; off < 64; off <<= 1) se += __shfl_xor(se, off, 64);
  float den = mm + __logf(se);
  if (lane == 0) {
    float num = acc + start_t[yb[0]] + end_t[yb[L - 1]];
    partials[b] = num - den;
  }
}

// ---------------- K4: final reduce ------------------------------------------
__global__ void finalize_kernel(const float* __restrict__ partials, float* __restrict__ out) {
  int l = threadIdx.x;
  float v = partials[l];
#pragma unroll
  for (int off = 32; off >= 1; off >>= 1) v += __shfl_down(v, off, 64);
  if (l == 0) out[0] = -v;
}

extern "C" void kernel_launch(void* const* d_in, const int* in_sizes, int n_in,
                              void* d_out, int out_size, void* d_ws, size_t ws_size,
                              hipStream_t stream) {
  const int*   x     = (const int*)d_in[0];
  const int*   seqln = (const int*)d_in[1];
  const int*   y     = (const int*)d_in[2];
  const float* emb   = (const float*)d_in[3];
  const float* Wih_f = (const float*)d_in[4];
  const float* Whh_f = (const float*)d_in[5];
  const float* b_f   = (const float*)d_in[6];
  const float* Wih_b = (const float*)d_in[7];
  const float* Whh_b = (const float*)d_in[8];
  const float* b_b   = (const float*)d_in[9];
  const float* Wfc   = (const float*)d_in[10];
  const float* st    = (const float*)d_in[11];
  const float* en    = (const float*)d_in[12];
  const float* trans = (const float*)d_in[13];
  float* out = (float*)d_out;

  char* ws = (char*)d_ws;                         // total required ~91.7 MB
  short* WpackX   = (short*)(ws + 0);             // 2,097,152
  short* WpackH   = (short*)(ws + 2097152);       // 4,194,304
  short* WfcPack  = (short*)(ws + 6291456);       //    32,768
  short* xpack    = (short*)(ws + 6324224);       // 16,777,216
  short* hping    = (short*)(ws + 23101440);      //   262,144
  int*   flags    = (int*)  (ws + 23363584);      //     1,024
  float* partials = (float*)(ws + 23364608);      //       256
  float* logits   = (float*)(ws + 23364864);      // 1,179,648
  short* hhist    = (short*)(ws + 24544512);      // 67,108,864 -> end 91,653,376

  pack_weights<<<64, 256, 0, stream>>>(Wih_f, Whh_f, Wih_b, Whh_b, Wfc,
                                       WpackX, WpackH, WfcPack);
  pack_x<<<4096, 256, 0, stream>>>(x, emb, xpack);
  init_state<<<1, 256, 0, stream>>>(flags);
  lstm_step_kernel<<<64, 256, 0, stream>>>((const short8*)xpack, WpackX, WpackH,
                                           hping, flags, hhist, b_f, b_b, seqln);
  emis_kernel<<<256, 256, 0, stream>>>(hhist, WfcPack, logits);
  crf_kernel<<<64, 64, 0, stream>>>(logits, y, seqln, st, en, trans, partials);
  finalize_kernel<<<1, 64, 0, stream>>>(partials, out);
}

// Round 5
// 4889.817 us; speedup vs baseline: 1.0262x; 1.0262x over previous
//
#include <hip/hip_runtime.h>
#include <hip/hip_bf16.h>

// BiLSTM-CRF loss, MI355X. B=64 T=512 V=30000 E=256 H=512 C=9.
// Round 5: round-3 structure with de-contended per-wave flag cache lines
// (128B each), single-dword-per-lane polling, issue-all h-loads with counted
// vmcnt, register-resident Wih/Whh, gathered 16B exchange stores, hhist off
// the critical path. No LDS in the LSTM kernel.

using short8 = __attribute__((ext_vector_type(8))) short;   // 8 x bf16 bits
using f32x4  = __attribute__((ext_vector_type(4))) float;
using i32x4  = __attribute__((ext_vector_type(4))) int;

#define TT 512
#define BB 64

__device__ __forceinline__ unsigned short f2bf(float f) {
  unsigned int u = __builtin_bit_cast(unsigned int, f);
  u += 0x7FFFu + ((u >> 16) & 1u);           // RNE
  return (unsigned short)(u >> 16);
}
__device__ __forceinline__ float bf2f(short s) {
  unsigned int u = ((unsigned int)(unsigned short)s) << 16;
  return __builtin_bit_cast(float, u);
}
__device__ __forceinline__ float fast_rcp(float x) { return __builtin_amdgcn_rcpf(x); }
__device__ __forceinline__ float sigmoid_f(float x) { return fast_rcp(1.f + __expf(-x)); }
__device__ __forceinline__ float tanh_f(float x) {
  float e = __expf(-2.f * fabsf(x));
  float r = (1.f - e) * fast_rcp(1.f + e);
  return copysignf(r, x);
}
#define SEL4(i, a0, a1, a2, a3) ((i)==0?(a0):((i)==1?(a1):((i)==2?(a2):(a3))))

// ---- uncached (coherence-point) ops: sc0 sc1 ----
__device__ __forceinline__ i32x4 load16_sc(const void* p) {      // no wait
  i32x4 r;
  asm volatile("global_load_dwordx4 %0, %1, off sc0 sc1" : "=v"(r) : "v"(p));
  return r;
}
__device__ __forceinline__ int load4_sc_wait(const void* p) {    // self-waiting
  int r;
  asm volatile("global_load_dword %0, %1, off sc0 sc1\n\ts_waitcnt vmcnt(0)"
               : "=v"(r) : "v"(p) : "memory");
  return r;
}
__device__ __forceinline__ void store16_sc(void* p, i32x4 v) {
  asm volatile("global_store_dwordx4 %0, %1, off sc0 sc1" :: "v"(p), "v"(v) : "memory");
}
#define WAITV(n) do { asm volatile("s_waitcnt vmcnt(" #n ")" ::: "memory"); \
                      __builtin_amdgcn_sched_barrier(0); } while (0)

// ---------------- K0a: pack LSTM + FC weights to bf16 -----------------------
// LSTM col n in [0,64) of block bid (d=bid&1, sl=bid>>1):
//   gate g=n&3, jq=(n>>2)&3, tj=(n>>4)&1, nt=n>>5 -> unit jj = nt*8+jq*2+tj,
//   weight row r = g*512 + sl*16 + jj.  (unit permutation enables wide stores)
__global__ void pack_weights(const float* __restrict__ Wih_f, const float* __restrict__ Whh_f,
                             const float* __restrict__ Wih_b, const float* __restrict__ Whh_b,
                             const float* __restrict__ Wfc,
                             short* __restrict__ WpackX, short* __restrict__ WpackH,
                             short* __restrict__ WfcPack) {
  const int bid = blockIdx.x;
  const int d = bid & 1, sl = bid >> 1;
  const float* Wih = d ? Wih_b : Wih_f;
  const float* Whh = d ? Whh_b : Whh_f;
  for (int idx = threadIdx.x; idx < 64 * 256; idx += 256) {
    int n = idx >> 8, k = idx & 255;
    int g = n & 3, jq = (n >> 2) & 3, tj = (n >> 4) & 1, nt = n >> 5;
    int r = g * 512 + sl * 16 + nt * 8 + jq * 2 + tj;
    WpackX[((size_t)bid * 64 + n) * 256 + k] = (short)f2bf(Wih[(size_t)r * 256 + k]);
  }
  for (int idx = threadIdx.x; idx < 64 * 512; idx += 256) {
    int n = idx >> 9, k = idx & 511;
    int g = n & 3, jq = (n >> 2) & 3, tj = (n >> 4) & 1, nt = n >> 5;
    int r = g * 512 + sl * 16 + nt * 8 + jq * 2 + tj;
    WpackH[((size_t)bid * 64 + n) * 512 + k] = (short)f2bf(Whh[(size_t)r * 512 + k]);
  }
  if (bid == 0) {
    for (int idx = threadIdx.x; idx < 16 * 1024; idx += 256) {
      int c = idx >> 10, k = idx & 1023;
      WfcPack[idx] = (c < 9) ? (short)f2bf(Wfc[c * 1024 + k]) : (short)0;
    }
  }
}

// ---------------- K0b: gather embeddings into MFMA A-fragment layout --------
__global__ void pack_x(const int* __restrict__ x, const float* __restrict__ emb,
                       short* __restrict__ xpack) {
  int gid = blockIdx.x * 256 + threadIdx.x;     // < 1048576
  int lane = gid & 63;
  int kc = (gid >> 6) & 7;
  int mt = (gid >> 9) & 3;
  int t  = gid >> 11;
  int b  = mt * 16 + (lane & 15);
  int k0 = kc * 32 + (lane >> 4) * 8;
  int vid = x[b * TT + t];
  const float* e = emb + (size_t)vid * 256 + k0;
  short8 v;
#pragma unroll
  for (int i = 0; i < 8; ++i) v[i] = (short)f2bf(e[i]);
  *reinterpret_cast<short8*>(xpack + (size_t)gid * 8) = v;
}

// ---------------- K0c: zero flags (4 groups x 64 waves x 128B line) ---------
__global__ void init_state(int* __restrict__ flags) {
  int gid = blockIdx.x * 256 + threadIdx.x;
  if (gid < 8192) flags[gid] = 0;
}

// ---------------- K1: persistent flag-synced BiLSTM -------------------------
// 64 WGs x 256 thr. WG: d=bid&1, sl=bid>>1 owns 16 units x 4 gates.
// Wave (mtb=wv&1, nt=wv>>1): rows [mtb*32,+32) x 8 units.
// flags: [(d*2+mtb)][g=sl*2+nt] each padded to its own 128B line.
// Per step: x-MFMA (regs) -> poll 64 flags (1 dword/lane, distinct lines) ->
// issue all 32 sc h-loads -> vmcnt(16) -> h-MFMA kc0..7 -> vmcnt(0) ->
// h-MFMA kc8..15 -> gates/state -> gathered 16B sc store -> vmcnt ack ->
// flag publish -> hhist stores (off critical path).
__launch_bounds__(256, 1)
__global__ void lstm_step_kernel(const short8* __restrict__ xpack,
                                 const short* __restrict__ WpackX,
                                 const short* __restrict__ WpackH,
                                 short* __restrict__ hping,   // [2][2][64][512]
                                 int* __restrict__ flags,     // [4][64][32]
                                 short* __restrict__ hhist,   // [2][512][64][512]
                                 const float* __restrict__ b_f,
                                 const float* __restrict__ b_b,
                                 const int* __restrict__ seq_len) {
  const int bid = blockIdx.x;
  const int d = bid & 1;
  const int sl = bid >> 1;
  const int tid = threadIdx.x;
  const int wv = tid >> 6;
  const int lane = tid & 63;
  const int l15 = lane & 15;
  const int lhi = lane >> 4;
  const int q = lane & 3;          // gate id of this lane's column
  const int jq = l15 >> 2;
  const int mtb = wv & 1;          // wave's row half
  const int nt = wv >> 1;          // wave's 8-unit group
  const int mbase = mtb * 32;
  const int nbase = nt * 32;
  const int ubase = sl * 16 + nt * 8;            // wave's 8-unit base

  // Wih + Whh B-fragments, register-resident for the whole kernel.
  short8 bfx[2][8];
#pragma unroll
  for (int tj = 0; tj < 2; ++tj)
#pragma unroll
    for (int kc = 0; kc < 8; ++kc)
      bfx[tj][kc] = *reinterpret_cast<const short8*>(
          WpackX + ((size_t)bid * 64 + nbase + tj * 16 + l15) * 256 + kc * 32 + lhi * 8);
  short8 bfh[2][16];
#pragma unroll
  for (int tj = 0; tj < 2; ++tj)
#pragma unroll
    for (int kc = 0; kc < 16; ++kc)
      bfh[tj][kc] = *reinterpret_cast<const short8*>(
          WpackH + ((size_t)bid * 64 + nbase + tj * 16 + l15) * 512 + kc * 32 + lhi * 8);

  const float* bias = d ? b_b : b_f;
  float bi[2], bfg[2], bgg[2], bog[2];
#pragma unroll
  for (int tj = 0; tj < 2; ++tj) {
    int jg = ubase + jq * 2 + tj;
    bi[tj]  = bias[jg];
    bfg[tj] = bias[512 + jg];
    bgg[tj] = bias[1024 + jg];
    bog[tj] = bias[1536 + jg];
  }
  int brow[2], Lr[2];
#pragma unroll
  for (int ti = 0; ti < 2; ++ti) {
    brow[ti] = mbase + ti * 16 + lhi * 4 + q;   // this lane's batch row
    Lr[ti] = seq_len[brow[ti]];
  }
  float cst[2][2] = {{0.f, 0.f}, {0.f, 0.f}};
  float hst[2][2] = {{0.f, 0.f}, {0.f, 0.f}};

  int* fl_grp  = flags + (d * 2 + mtb) * 64 * 32;             // group base
  int* fl_mine = fl_grp + (sl * 2 + nt) * 32;                 // own 128B line
  const int* fl_poll = fl_grp + lane * 32;                    // lane's line

  for (int s = 0; s < TT; ++s) {
    const int t = d ? (TT - 1 - s) : s;
    f32x4 acc[2][2];
#pragma unroll
    for (int ti = 0; ti < 2; ++ti)
#pragma unroll
      for (int tj = 0; tj < 2; ++tj) acc[ti][tj] = (f32x4){0.f, 0.f, 0.f, 0.f};

    // ---- Phase A: x@Wih^T (no sequential dependency; overlaps poll tail) ---
    const short8* xp = xpack + (size_t)t * 2048;
#pragma unroll
    for (int kc = 0; kc < 8; ++kc) {
      short8 af[2];
#pragma unroll
      for (int ti = 0; ti < 2; ++ti)
        af[ti] = xp[((mtb * 2 + ti) * 8 + kc) * 64 + lane];
#pragma unroll
      for (int ti = 0; ti < 2; ++ti)
#pragma unroll
        for (int tj = 0; tj < 2; ++tj)
          acc[ti][tj] = __builtin_amdgcn_mfma_f32_16x16x32_bf16(af[ti], bfx[tj][kc], acc[ti][tj], 0, 0, 0);
    }

    if (s > 0) {
      // ---- Phase B: poll the 64 producer flags (1 dword/lane, own line) ----
      {
        int vtries = 0;
        while (true) {
          int f = load4_sc_wait(fl_poll);
          if (__all(f >= s)) break;
          __builtin_amdgcn_s_sleep(1);
          if (++vtries > (1 << 17)) break;     // anti-hang valve
        }
      }
      __builtin_amdgcn_sched_barrier(0);

      // ---- Phase C: issue all 32 h-loads, then MFMA with counted waits ----
      const short* hp = hping + ((size_t)(d * 2 + (s & 1)) * 64) * 512;
      i32x4 hbuf[32];
#pragma unroll
      for (int kc = 0; kc < 16; ++kc)
#pragma unroll
        for (int ti = 0; ti < 2; ++ti)
          hbuf[kc * 2 + ti] =
              load16_sc(hp + (mbase + ti * 16 + l15) * 512 + kc * 32 + lhi * 8);
      WAITV(16);                                // first 16 loads (kc 0..7) done
#pragma unroll
      for (int kc = 0; kc < 8; ++kc)
#pragma unroll
        for (int ti = 0; ti < 2; ++ti) {
          short8 a = __builtin_bit_cast(short8, hbuf[kc * 2 + ti]);
#pragma unroll
          for (int tj = 0; tj < 2; ++tj)
            acc[ti][tj] = __builtin_amdgcn_mfma_f32_16x16x32_bf16(a, bfh[tj][kc], acc[ti][tj], 0, 0, 0);
        }
      WAITV(0);                                 // remaining 16 loads done
#pragma unroll
      for (int kc = 8; kc < 16; ++kc)
#pragma unroll
        for (int ti = 0; ti < 2; ++ti) {
          short8 a = __builtin_bit_cast(short8, hbuf[kc * 2 + ti]);
#pragma unroll
          for (int tj = 0; tj < 2; ++tj)
            acc[ti][tj] = __builtin_amdgcn_mfma_f32_16x16x32_bf16(a, bfh[tj][kc], acc[ti][tj], 0, 0, 0);
        }
    }

    // ---- Phase D: gates via 4-lane shuffles, state update ----
    short* hpo = hping + ((size_t)(d * 2 + ((s + 1) & 1)) * 64) * 512;
    unsigned int hh32[2];
#pragma unroll
    for (int ti = 0; ti < 2; ++ti) {
      bool m = (t < Lr[ti]);
      unsigned short hnb[2], htb[2];
#pragma unroll
      for (int tj = 0; tj < 2; ++tj) {
        f32x4 A = acc[ti][tj];
        float a0 = A[0], a1 = A[1], a2 = A[2], a3 = A[3];
        float e10 = __shfl_xor(a0, 1, 64), e11 = __shfl_xor(a1, 1, 64),
              e12 = __shfl_xor(a2, 1, 64), e13 = __shfl_xor(a3, 1, 64);
        float e20 = __shfl_xor(a0, 2, 64), e21 = __shfl_xor(a1, 2, 64),
              e22 = __shfl_xor(a2, 2, 64), e23 = __shfl_xor(a3, 2, 64);
        float e30 = __shfl_xor(a0, 3, 64), e31 = __shfl_xor(a1, 3, 64),
              e32 = __shfl_xor(a2, 3, 64), e33 = __shfl_xor(a3, 3, 64);
        float g0 = SEL4(q, a0, a1, a2, a3);
        float g1 = SEL4(q, e10, e11, e12, e13);
        float g2 = SEL4(q, e20, e21, e22, e23);
        float g3 = SEL4(q, e30, e31, e32, e33);
        float gi = SEL4(q,     g0, g1, g2, g3) + bi[tj];
        float gf = SEL4(q ^ 1, g0, g1, g2, g3) + bfg[tj];
        float gg = SEL4(q ^ 2, g0, g1, g2, g3) + bgg[tj];
        float go = SEL4(q ^ 3, g0, g1, g2, g3) + bog[tj];
        float si = sigmoid_f(gi), sf = sigmoid_f(gf), so = sigmoid_f(go);
        float ct = sf * cst[ti][tj] + si * tanh_f(gg);
        float ht = so * tanh_f(ct);
        float cn = m ? ct : cst[ti][tj];
        float hn = m ? ht : hst[ti][tj];
        cst[ti][tj] = cn;
        hst[ti][tj] = hn;
        hnb[tj] = f2bf(hn);
        htb[tj] = m ? f2bf(ht) : (unsigned short)0;
      }
      unsigned int up = ((unsigned int)hnb[1] << 16) | hnb[0];
      unsigned int uh = ((unsigned int)htb[1] << 16) | htb[0];
      // gather the row's 4 unit-pairs (jq=0..3 at lanes +4,+8,+12) into jq==0
      unsigned int p1 = __shfl_xor(up, 4, 64), p2 = __shfl_xor(up, 8, 64),
                   p3 = __shfl_xor(up, 12, 64);
      unsigned int q1 = __shfl_xor(uh, 4, 64), q2 = __shfl_xor(uh, 8, 64),
                   q3 = __shfl_xor(uh, 12, 64);
      hh32[0] = q1; hh32[1] = q3;   // stash (only used below by jq==0 lanes)
      if (jq == 0) {
        i32x4 packp = {(int)up, (int)p1, (int)p2, (int)p3};
        store16_sc(hpo + brow[ti] * 512 + ubase, packp);
        hh32[0] = uh; hh32[1] = q2; // reuse regs: {uh,q1,q2,q3} kept live
      }
      // publish + history handled after both ti below; keep htb packs:
      if (ti == 0) { /* fallthrough */ }
      // store hhist for this ti (cached, after flag below would be ideal;
      // issue now into a register pack, written after flag publish)
      if (jq == 0) {
        i32x4 packh = {(int)(ti == 0 ? hh32[0] : hh32[0]), (int)q1, (int)q2, (int)q3};
        // overwrite element 0 correctly (uh stored in hh32[0] for jq==0)
        packh[0] = (int)uh; packh[1] = (int)q1; packh[2] = (int)q2; packh[3] = (int)q3;
        // defer: write directly; these are cached stores on a separate path
        *reinterpret_cast<i32x4*>(
            &hhist[(((size_t)d * TT + t) * 64 + brow[ti]) * 512 + ubase]) = packh;
      }
    }
    // ---- Phase E: ack own sc-stores, publish flag ----
    {
      int sv = s + 1;
      // s_waitcnt is wave-granular: covers all lanes' outstanding stores.
      if (lane == 0) {
        asm volatile("s_waitcnt vmcnt(0)\n\t"
                     "global_store_dword %0, %1, off sc0 sc1"
                     :: "v"(fl_mine), "v"(sv) : "memory");
      }
    }
  }
}

// ---------------- K2: emission logits = [hf|hb] @ Wfc^T via MFMA ------------
__launch_bounds__(256)
__global__ void emis_kernel(const short* __restrict__ hhist,
                            const short* __restrict__ WfcPack,
                            float* __restrict__ logits) {
  __shared__ short wfc[16 * 1032];             // padded stride vs bank conflicts
  const int tid = threadIdx.x;
  for (int idx = tid; idx < 2048; idx += 256) {
    int n = idx >> 7, c8 = idx & 127;
    short8 v = *reinterpret_cast<const short8*>(WfcPack + n * 1024 + c8 * 8);
    *reinterpret_cast<short8*>(&wfc[n * 1032 + c8 * 8]) = v;
  }
  __syncthreads();
  const int wv = tid >> 6, lane = tid & 63;
  const int l15 = lane & 15, lhi = lane >> 4;
#pragma unroll
  for (int mt2 = 0; mt2 < 2; ++mt2) {
    int m = (blockIdx.x * 4 + wv) * 2 + mt2;
    int r0 = m * 16;
    f32x4 acc = (f32x4){0.f, 0.f, 0.f, 0.f};
#pragma unroll
    for (int kc = 0; kc < 32; ++kc) {
      const short* pa = hhist + ((kc < 16) ? 0 : (size_t)16777216)
                        + (size_t)(r0 + l15) * 512 + (kc & 15) * 32 + lhi * 8;
      short8 a = *reinterpret_cast<const short8*>(pa);
      short8 b = *reinterpret_cast<const short8*>(&wfc[l15 * 1032 + kc * 32 + lhi * 8]);
      acc = __builtin_amdgcn_mfma_f32_16x16x32_bf16(a, b, acc, 0, 0, 0);
    }
    int c = l15;
    if (c < 9) {
#pragma unroll
      for (int reg = 0; reg < 4; ++reg) {
        int rr = r0 + lhi * 4 + reg;
        int b = rr & 63, t = rr >> 6;
        logits[((size_t)b * TT + t) * 9 + c] = acc[reg];
      }
    }
  }
}

// ---------------- K3: CRF numerator + forward algorithm per batch -----------
__global__ void crf_kernel(const float* __restrict__ logits, const int* __restrict__ y,
                           const int* __restrict__ seq_len, const float* __restrict__ start_t,
                           const float* __restrict__ end_t, const float* __restrict__ trans,
                           float* __restrict__ partials) {
  const int b = blockIdx.x;
  const int lane = threadIdx.x;          // 64
  const float* lg = logits + (size_t)b * TT * 9;
  const int* yb = y + b * TT;
  const int L = seq_len[b];

  float acc = 0.f;
  for (int t = lane; t < TT; t += 64) {
    if (t < L) {
      float mx = lg[t * 9];
      for (int c = 1; c < 9; ++c) mx = fmaxf(mx, lg[t * 9 + c]);
      float se = 0.f;
      for (int c = 0; c < 9; ++c) se += __expf(lg[t * 9 + c] - mx);
      float lse = mx + __logf(se);
      int yt = yb[t];
      acc += lg[t * 9 + yt] - lse;
      if (t >= 1) acc += trans[yb[t - 1] * 9 + yt];
    }
  }
#pragma unroll
  for (int off = 32; off >= 1; off >>= 1) acc += __shfl_down(acc, off, 64);

  const int c = (lane < 9) ? lane : 0;
  float score;
  {
    float mx = lg[0];
    for (int cc = 1; cc < 9; ++cc) mx = fmaxf(mx, lg[cc]);
    float se = 0.f;
    for (int cc = 0; cc < 9; ++cc) se += __expf(lg[cc] - mx);
    score = start_t[c] + lg[c] - (mx + __logf(se));
  }
  float tr[9];
#pragma unroll
  for (int cc = 0; cc < 9; ++cc) tr[cc] = trans[cc * 9 + c];
  for (int t = 1; t < L; ++t) {
    const float* lt = lg + t * 9;
    float mx2 = lt[0];
    for (int cc = 1; cc < 9; ++cc) mx2 = fmaxf(mx2, lt[cc]);
    float se2 = 0.f;
    for (int cc = 0; cc < 9; ++cc) se2 += __expf(lt[cc] - mx2);
    float em = lt[c] - (mx2 + __logf(se2));
    float vv[9];
    float mx = -1e30f;
#pragma unroll
    for (int cc = 0; cc < 9; ++cc) {
      float sp = __shfl(score, cc, 64);
      vv[cc] = sp + tr[cc];
      mx = fmaxf(mx, vv[cc]);
    }
    float se = 0.f;
#pragma unroll
    for (int cc = 0; cc < 9; ++cc) se += __expf(vv[cc] - mx);
    score = mx + __logf(se) + em;
  }
  float val = (lane < 9) ? (score + end_t[lane]) : -1e30f;
  float mm = val;
#pragma unroll
  for (int off = 1; off < 64; off <<= 1) mm = fmaxf(mm, __shfl_xor(mm, off, 64));
  float se = (lane < 9) ? __expf(val - mm) : 0.f;
#pragma unroll
  for (int off = 1; off < 64; off <<= 1) se += __shfl_xor(se, off, 64);
  float den = mm + __logf(se);
  if (lane == 0) {
    float num = acc + start_t[yb[0]] + end_t[yb[L - 1]];
    partials[b] = num - den;
  }
}

// ---------------- K4: final reduce ------------------------------------------
__global__ void finalize_kernel(const float* __restrict__ partials, float* __restrict__ out) {
  int l = threadIdx.x;
  float v = partials[l];
#pragma unroll
  for (int off = 32; off >= 1; off >>= 1) v += __shfl_down(v, off, 64);
  if (l == 0) out[0] = -v;
}

extern "C" void kernel_launch(void* const* d_in, const int* in_sizes, int n_in,
                              void* d_out, int out_size, void* d_ws, size_t ws_size,
                              hipStream_t stream) {
  const int*   x     = (const int*)d_in[0];
  const int*   seqln = (const int*)d_in[1];
  const int*   y     = (const int*)d_in[2];
  const float* emb   = (const float*)d_in[3];
  const float* Wih_f = (const float*)d_in[4];
  const float* Whh_f = (const float*)d_in[5];
  const float* b_f   = (const float*)d_in[6];
  const float* Wih_b = (const float*)d_in[7];
  const float* Whh_b = (const float*)d_in[8];
  const float* b_b   = (const float*)d_in[9];
  const float* Wfc   = (const float*)d_in[10];
  const float* st    = (const float*)d_in[11];
  const float* en    = (const float*)d_in[12];
  const float* trans = (const float*)d_in[13];
  float* out = (float*)d_out;

  char* ws = (char*)d_ws;                         // total required ~91.7 MB
  short* WpackX   = (short*)(ws + 0);             // 2,097,152
  short* WpackH   = (short*)(ws + 2097152);       // 4,194,304
  short* WfcPack  = (short*)(ws + 6291456);       //    32,768
  short* xpack    = (short*)(ws + 6324224);       // 16,777,216
  short* hping    = (short*)(ws + 23101440);      //   262,144
  int*   flags    = (int*)  (ws + 23363584);      //    32,768 (4x64x128B)
  float* partials = (float*)(ws + 23396352);      //       256
  float* logits   = (float*)(ws + 23396608);      // 1,179,648
  short* hhist    = (short*)(ws + 24576256);      // 67,108,864 -> end 91,685,120

  pack_weights<<<64, 256, 0, stream>>>(Wih_f, Whh_f, Wih_b, Whh_b, Wfc,
                                       WpackX, WpackH, WfcPack);
  pack_x<<<4096, 256, 0, stream>>>(x, emb, xpack);
  init_state<<<32, 256, 0, stream>>>(flags);
  lstm_step_kernel<<<64, 256, 0, stream>>>((const short8*)xpack, WpackX, WpackH,
                                           hping, flags, hhist, b_f, b_b, seqln);
  emis_kernel<<<256, 256, 0, stream>>>(hhist, WfcPack, logits);
  crf_kernel<<<64, 64, 0, stream>>>(logits, y, seqln, st, en, trans, partials);
  finalize_kernel<<<1, 64, 0, stream>>>(partials, out);
}